// Round 5
// baseline (50.963 us; speedup 1.0000x reference)
//
#include <hip/hip_runtime.h>
#include <math.h>

#define N_T   16384
#define BLOCK 1024
#define SEG   16            // elements per thread
#define NWAVE 16            // waves per block

// MODE 0: d_out = real part only, flat (16,64,16384) float32  (out_size = N)
// MODE 1: d_out = interleaved re/im pairs                     (out_size = 2N)
template <int MODE>
__global__ __launch_bounds__(BLOCK)
void phase_kernel(const float* __restrict__ x, float* __restrict__ out) {
    __shared__ int   wsum[NWAVE];    // wave jump-sum totals
    __shared__ float wedgeL[NWAVE];  // corrected first elem of each wave
    __shared__ float wedgeR[NWAVE];  // corrected last elem of each wave

    const int tid  = threadIdx.x;
    const int lane = tid & 63;
    const int wv   = tid >> 6;
    const int r    = blockIdx.x;         // row in [0, 1024)
    const int b    = r >> 6;             // batch
    const int c    = r & 63;             // channel
    const float* __restrict__ phase_row = x + ((size_t)(b * 128 + 64 + c)) * N_T;
    const float* __restrict__ mag_row   = x + ((size_t)(b * 128 + c)) * N_T;

    const float TWO_PI = 6.28318530717958647692f;  // f32 0x40C90FDB
    const float PI_F   = 3.14159265358979323846f;
    const float THIRD  = 1.0f / 3.0f;

    const int seg0 = tid * SEG;

    // ---- 1. issue phase-segment loads, then mag loads (mag stays in flight
    //         through the scan; vmcnt waits are counted, so waiting on the
    //         phase loads does not drain the mag loads)
    float4 p0 = *reinterpret_cast<const float4*>(phase_row + seg0);
    float4 p1 = *reinterpret_cast<const float4*>(phase_row + seg0 + 4);
    float4 p2 = *reinterpret_cast<const float4*>(phase_row + seg0 + 8);
    float4 p3 = *reinterpret_cast<const float4*>(phase_row + seg0 + 12);
    float4 m0 = *reinterpret_cast<const float4*>(mag_row + seg0);
    float4 m1 = *reinterpret_cast<const float4*>(mag_row + seg0 + 4);
    float4 m2 = *reinterpret_cast<const float4*>(mag_row + seg0 + 8);
    float4 m3 = *reinterpret_cast<const float4*>(mag_row + seg0 + 12);

    float s[SEG] = {p0.x, p0.y, p0.z, p0.w, p1.x, p1.y, p1.z, p1.w,
                    p2.x, p2.y, p2.z, p2.w, p3.x, p3.y, p3.z, p3.w};

    // raw value just before this segment
    float prevseg = __shfl_up(s[SEG - 1], 1);
    if (lane == 0) prevseg = (tid > 0) ? phase_row[seg0 - 1] : 0.0f;

    // ---- 2. local jump-sum
    int lsum = 0;
    {
        float prev = prevseg;
        #pragma unroll
        for (int j = 0; j < SEG; ++j) {
            float g = s[j] - prev;
            if ((seg0 + j) > 0 && fabsf(g) > 0.5f) lsum += (g > 0.0f) ? 1 : -1;
            prev = s[j];
        }
    }

    // ---- 3. wave-inclusive scan (registers), then cross-wave via 64B LDS
    int incl = lsum;
    #pragma unroll
    for (int off = 1; off < 64; off <<= 1) {
        int n = __shfl_up(incl, off);
        if (lane >= off) incl += n;
    }
    if (lane == 63) wsum[wv] = incl;
    __syncthreads();                               // barrier #1
    int wpre = 0;
    #pragma unroll
    for (int w = 0; w < NWAVE; ++w) {
        int wt = wsum[w];                          // wave-uniform broadcast
        if (w < wv) wpre += wt;
    }
    int running = wpre + incl - lsum;              // exclusive prefix = corr[seg0]

    // ---- 4. corrected phase, in place
    {
        float prev = prevseg;
        #pragma unroll
        for (int j = 0; j < SEG; ++j) {
            float cur = s[j];
            int d = 0;
            if ((seg0 + j) > 0) {
                float g = cur - prev;
                if (fabsf(g) > 0.5f) d = (g > 0.0f) ? 1 : -1;
            }
            s[j] = (cur - (float)running) * TWO_PI - PI_F;
            running += d;
            prev = cur;
        }
    }

    // ---- 5. corrected-phase neighbors: shuffles + wave-edge LDS
    if (lane == 0)  wedgeL[wv] = s[0];
    if (lane == 63) wedgeR[wv] = s[SEG - 1];
    __syncthreads();                               // barrier #2
    float left = __shfl_up(s[SEG - 1], 1);
    if (lane == 0)  left  = (wv > 0)     ? wedgeR[wv - 1] : 0.0f;   // tid==0: zero pad
    float right = __shfl_down(s[0], 1);
    if (lane == 63) right = (wv < NWAVE - 1) ? wedgeL[wv + 1] : 0.0f; // tid==1023: zero pad

    // ---- 6. smooth + blend + range-reduced cos/sin + store (64B/thread)
    float mgk[SEG] = {m0.x, m0.y, m0.z, m0.w, m1.x, m1.y, m1.z, m1.w,
                      m2.x, m2.y, m2.z, m2.w, m3.x, m3.y, m3.z, m3.w};
    float re[SEG], im[SEG];
    #pragma unroll
    for (int j = 0; j < SEG; ++j) {
        float pm = (j == 0)       ? left  : s[j - 1];
        float pp = (j == SEG - 1) ? right : s[j + 1];
        float sm = ((pm + s[j]) + pp) * THIRD;
        float pf = 0.7f * s[j] + 0.3f * sm;
        // two-term range reduction: 2pi = hi + lo
        float nrev = rintf(pf * 0.15915494309189535f);
        float rr = fmaf(nrev, -6.28318548202514648f, pf);
        rr = fmaf(nrev, 1.74845553e-7f, rr);
        re[j] = mgk[j] * __cosf(rr);
        if (MODE == 1) im[j] = mgk[j] * __sinf(rr);
    }
    if (MODE == 0) {
        float* o = out + (size_t)r * N_T + seg0;
        #pragma unroll
        for (int q = 0; q < SEG / 4; ++q)
            *reinterpret_cast<float4*>(o + q * 4) =
                make_float4(re[q*4], re[q*4+1], re[q*4+2], re[q*4+3]);
    } else {
        float* o = out + (size_t)r * (2 * N_T) + 2 * seg0;
        #pragma unroll
        for (int q = 0; q < SEG / 2; ++q)
            *reinterpret_cast<float4*>(o + q * 4) =
                make_float4(re[q*2], im[q*2], re[q*2+1], im[q*2+1]);
    }
}

extern "C" void kernel_launch(void* const* d_in, const int* in_sizes, int n_in,
                              void* d_out, int out_size, void* d_ws, size_t ws_size,
                              hipStream_t stream) {
    const float* x = (const float*)d_in[0];
    float* out = (float*)d_out;
    int n_rows = in_sizes[0] / (2 * N_T);            // 1024
    if (out_size >= in_sizes[0]) {
        phase_kernel<1><<<n_rows, BLOCK, 0, stream>>>(x, out);
    } else {
        phase_kernel<0><<<n_rows, BLOCK, 0, stream>>>(x, out);
    }
}

// Round 6
// 49.489 us; speedup vs baseline: 1.0298x; 1.0298x over previous
//
#include <hip/hip_runtime.h>
#include <math.h>

#define N_T   16384
#define BLOCK 1024
#define SEG   16            // elements per thread
#define NWAVE 16            // waves per block

// XOR-swizzle word index: mix bits [6:8] into bits [2:4].
// Preserves 16B (float4) granularity; bijective within [0, 16384).
__device__ __forceinline__ int SW(int i) {
    return i ^ (((i >> 6) & 7) << 2);
}

// MODE 0: d_out = real part only, flat (16,64,16384) float32  (out_size = N)
// MODE 1: d_out = interleaved re/im pairs                     (out_size = 2N)
template <int MODE>
__global__ __launch_bounds__(BLOCK, 8)
void phase_kernel(const float* __restrict__ x, float* __restrict__ out) {
    __shared__ float ph[N_T];   // exactly 64 KiB static LDS

    const int tid  = threadIdx.x;
    const int lane = tid & 63;
    const int wave = tid >> 6;
    const int r    = blockIdx.x;         // row in [0, 1024)
    const int b    = r >> 6;             // batch
    const int c    = r & 63;             // channel
    const float* __restrict__ phase_row = x + ((size_t)(b * 128 + 64 + c)) * N_T;
    const float* __restrict__ mag_row   = x + ((size_t)(b * 128 + c)) * N_T;

    const float TWO_PI = 6.28318530717958647692f;  // f32 0x40C90FDB
    const float PI_F   = 3.14159265358979323846f;
    const float THIRD  = 1.0f / 3.0f;

    // ---- 1. issue phase loads (coalesced), then mag prefetch (coalesced,
    //         output layout, held in regs through the scan). In-order vmcnt
    //         means staging only drains the phase loads; mag stays in flight.
    float4 p0, p1, p2, p3;
    {
        int i0 = (0 * BLOCK + tid) * 4, i1 = (1 * BLOCK + tid) * 4;
        int i2 = (2 * BLOCK + tid) * 4, i3 = (3 * BLOCK + tid) * 4;
        p0 = *reinterpret_cast<const float4*>(phase_row + i0);
        p1 = *reinterpret_cast<const float4*>(phase_row + i1);
        p2 = *reinterpret_cast<const float4*>(phase_row + i2);
        p3 = *reinterpret_cast<const float4*>(phase_row + i3);
    }
    float4 mg[4];
    #pragma unroll
    for (int i = 0; i < 4; ++i) {
        int idx = (i * BLOCK + tid) * 4;
        mg[i] = *reinterpret_cast<const float4*>(mag_row + idx);
    }
    {
        int i0 = (0 * BLOCK + tid) * 4, i1 = (1 * BLOCK + tid) * 4;
        int i2 = (2 * BLOCK + tid) * 4, i3 = (3 * BLOCK + tid) * 4;
        *reinterpret_cast<float4*>(&ph[SW(i0)]) = p0;
        *reinterpret_cast<float4*>(&ph[SW(i1)]) = p1;
        *reinterpret_cast<float4*>(&ph[SW(i2)]) = p2;
        *reinterpret_cast<float4*>(&ph[SW(i3)]) = p3;
    }
    __syncthreads();                                // sync 1: row staged

    // ---- 2. own contiguous segment into registers; local d-sum
    const int seg0 = tid * SEG;
    float s[SEG];
    #pragma unroll
    for (int q = 0; q < SEG / 4; ++q) {             // 4 x ds_read_b128
        float4 v = *reinterpret_cast<const float4*>(&ph[SW(seg0 + q * 4)]);
        s[q * 4 + 0] = v.x; s[q * 4 + 1] = v.y;
        s[q * 4 + 2] = v.z; s[q * 4 + 3] = v.w;
    }
    float prevseg = __shfl_up(s[SEG - 1], 1);       // last elem of prev thread
    if (lane == 0) prevseg = (tid > 0) ? ph[SW(seg0 - 1)] : 0.0f;

    int lsum = 0;
    {
        float prev = prevseg;
        #pragma unroll
        for (int j = 0; j < SEG; ++j) {
            float g = s[j] - prev;
            if ((seg0 + j) > 0 && fabsf(g) > 0.5f) lsum += (g > 0.0f) ? 1 : -1;
            prev = s[j];
        }
    }

    // ---- 3. wave-inclusive scan (registers) + cross-wave via ph[0..15]
    int incl = lsum;
    #pragma unroll
    for (int off = 1; off < 64; off <<= 1) {
        int n = __shfl_up(incl, off);
        if (lane >= off) incl += n;
    }
    __syncthreads();                                // sync 2: all raw reads done
    // publish wave totals into ph[0..15] (raw slots 0..15 are only ever read
    // by thread 0, which is in the same wave as the wave-0 publisher -> safe)
    if (lane == 63) ph[wave] = __int_as_float(incl);
    __syncthreads();                                // sync 3: totals visible
    int wpre = 0;
    #pragma unroll
    for (int w = 0; w < NWAVE; ++w) {
        int wt = __float_as_int(ph[w]);             // wave-uniform broadcast
        if (w < wave) wpre += wt;
    }
    int running = wpre + incl - lsum;               // exclusive prefix = corr[seg0]

    // ---- 4. corrected phase in registers
    {
        float prev = prevseg;
        #pragma unroll
        for (int j = 0; j < SEG; ++j) {
            float cur = s[j];
            int d = 0;
            if ((seg0 + j) > 0) {
                float g = cur - prev;
                if (fabsf(g) > 0.5f) d = (g > 0.0f) ? 1 : -1;
            }
            s[j] = (cur - (float)running) * TWO_PI - PI_F;
            running += d;
            prev = cur;
        }
    }
    __syncthreads();                                // sync 4: scan totals consumed
    #pragma unroll
    for (int q = 0; q < SEG / 4; ++q) {
        *reinterpret_cast<float4*>(&ph[SW(seg0 + q * 4)]) =
            make_float4(s[q * 4 + 0], s[q * 4 + 1], s[q * 4 + 2], s[q * 4 + 3]);
    }
    __syncthreads();                                // sync 5: corrected row staged

    // ---- 5. coalesced output pass (mag already in regs)
    #pragma unroll
    for (int i = 0; i < 4; ++i) {
        int e = (i * BLOCK + tid) * 4;
        float4 pc = *reinterpret_cast<const float4*>(&ph[SW(e)]);

        float p_m1 = __shfl_up(pc.w, 1);
        if (lane == 0)  p_m1 = (e > 0) ? ph[SW(e - 1)] : 0.0f;       // zero pad left
        float p_p4 = __shfl_down(pc.x, 1);
        if (lane == 63) p_p4 = (e + 4 < N_T) ? ph[SW(e + 4)] : 0.0f; // zero pad right

        float pv[6] = {p_m1, pc.x, pc.y, pc.z, pc.w, p_p4};
        float mgk[4] = {mg[i].x, mg[i].y, mg[i].z, mg[i].w};

        float re[4], im[4];
        #pragma unroll
        for (int k = 0; k < 4; ++k) {
            float sm = ((pv[k] + pv[k + 1]) + pv[k + 2]) * THIRD;
            float pf = 0.7f * pv[k + 1] + 0.3f * sm;
            // two-term range reduction: 2pi = hi + lo
            float nrev = rintf(pf * 0.15915494309189535f);
            float rr = fmaf(nrev, -6.28318548202514648f, pf);
            rr = fmaf(nrev, 1.74845553e-7f, rr);
            re[k] = mgk[k] * __cosf(rr);
            if (MODE == 1) im[k] = mgk[k] * __sinf(rr);
        }
        if (MODE == 0) {
            float* orow = out + (size_t)r * N_T;
            *reinterpret_cast<float4*>(orow + e) = make_float4(re[0], re[1], re[2], re[3]);
        } else {
            float* orow = out + (size_t)r * (2 * N_T);
            *reinterpret_cast<float4*>(orow + 2 * e) =
                make_float4(re[0], im[0], re[1], im[1]);
            *reinterpret_cast<float4*>(orow + 2 * e + 4) =
                make_float4(re[2], im[2], re[3], im[3]);
        }
    }
}

extern "C" void kernel_launch(void* const* d_in, const int* in_sizes, int n_in,
                              void* d_out, int out_size, void* d_ws, size_t ws_size,
                              hipStream_t stream) {
    const float* x = (const float*)d_in[0];
    float* out = (float*)d_out;
    int n_rows = in_sizes[0] / (2 * N_T);            // 1024
    if (out_size >= in_sizes[0]) {
        phase_kernel<1><<<n_rows, BLOCK, 0, stream>>>(x, out);
    } else {
        phase_kernel<0><<<n_rows, BLOCK, 0, stream>>>(x, out);
    }
}

// Round 7
// 36.048 us; speedup vs baseline: 1.4137x; 1.3728x over previous
//
#include <hip/hip_runtime.h>
#include <math.h>

#define N_T    16384
#define BLOCK  1024
#define NCH    4          // chunks per row; chunk = 4096 elems
#define CHSZ   4096
#define NWAVE  16

// MODE 0: d_out = real part only, flat (16,64,16384) float32  (out_size = N)
// MODE 1: d_out = interleaved re/im pairs                     (out_size = 2N)
template <int MODE>
__global__ __launch_bounds__(BLOCK)
void phase_kernel(const float* __restrict__ x, float* __restrict__ out) {
    // 1 KiB of LDS total — occupancy limited only by VGPRs
    __shared__ float rawEdge[NCH][NWAVE];  // raw .w of lane63, per chunk/wave
    __shared__ int   wtot[NCH][NWAVE];     // wave-inclusive jump totals
    __shared__ float corrR[NCH][NWAVE];    // corrected .w of lane63
    __shared__ float corrL[NCH][NWAVE];    // corrected .x of lane0

    const int tid  = threadIdx.x;
    const int lane = tid & 63;
    const int wv   = tid >> 6;
    const int r    = blockIdx.x;          // row in [0, 1024)
    const int b    = r >> 6;
    const int c    = r & 63;
    const float* __restrict__ phase_row = x + ((size_t)(b * 128 + 64 + c)) * N_T;
    const float* __restrict__ mag_row   = x + ((size_t)(b * 128 + c)) * N_T;

    const float TWO_PI = 6.28318530717958647692f;  // f32 0x40C90FDB
    const float PI_F   = 3.14159265358979323846f;
    const float THIRD  = 1.0f / 3.0f;

    // ---- 1. coalesced register load: chunk i, elements i*4096 + tid*4 .. +3
    float s[16];
    #pragma unroll
    for (int i = 0; i < NCH; ++i) {
        float4 v = *reinterpret_cast<const float4*>(phase_row + i * CHSZ + tid * 4);
        s[i * 4 + 0] = v.x; s[i * 4 + 1] = v.y;
        s[i * 4 + 2] = v.z; s[i * 4 + 3] = v.w;
    }

    // publish raw wave-edge values (lane63's .w per chunk)
    if (lane == 63) {
        #pragma unroll
        for (int i = 0; i < NCH; ++i) rawEdge[i][wv] = s[i * 4 + 3];
    }
    __syncthreads();                                   // barrier A

    // raw element just before each chunk-segment of this thread
    float prevRaw[NCH];
    #pragma unroll
    for (int i = 0; i < NCH; ++i) {
        float p = __shfl_up(s[i * 4 + 3], 1);
        if (lane == 0) {
            if (wv > 0)      p = rawEdge[i][wv - 1];
            else if (i > 0)  p = rawEdge[i - 1][NWAVE - 1];
            else             p = 0.0f;                 // t==0: d forced 0 below
        }
        prevRaw[i] = p;
    }

    // ---- 2. per-chunk local jump-counts (4 elements each)
    int lsum[NCH];
    #pragma unroll
    for (int i = 0; i < NCH; ++i) {
        float prev = prevRaw[i];
        int cnt = 0;
        #pragma unroll
        for (int k = 0; k < 4; ++k) {
            float cur = s[i * 4 + k];
            float g = cur - prev;
            bool first = (i == 0 && tid == 0 && k == 0);
            if (!first && fabsf(g) > 0.5f) cnt += (g > 0.0f) ? 1 : -1;
            prev = cur;
        }
        lsum[i] = cnt;
    }

    // ---- 3. four parallel wave-inclusive scans, then cross-wave/chunk prefix
    int incl[NCH] = {lsum[0], lsum[1], lsum[2], lsum[3]};
    #pragma unroll
    for (int off = 1; off < 64; off <<= 1) {
        #pragma unroll
        for (int i = 0; i < NCH; ++i) {
            int n = __shfl_up(incl[i], off);
            if (lane >= off) incl[i] += n;
        }
    }
    if (lane == 63) {
        #pragma unroll
        for (int i = 0; i < NCH; ++i) wtot[i][wv] = incl[i];
    }
    __syncthreads();                                   // barrier B

    int P[NCH];
    {
        int chunkPre = 0;
        #pragma unroll
        for (int i = 0; i < NCH; ++i) {
            int wpre = 0, tot = 0;
            #pragma unroll
            for (int w = 0; w < NWAVE; ++w) {
                int t = wtot[i][w];                    // wave-uniform broadcast
                if (w < wv) wpre += t;
                tot += t;
            }
            P[i] = chunkPre + wpre + (incl[i] - lsum[i]);  // exclusive prefix
            chunkPre += tot;
        }
    }

    // ---- 4. corrected phase in place
    #pragma unroll
    for (int i = 0; i < NCH; ++i) {
        int running = P[i];
        float prev = prevRaw[i];
        #pragma unroll
        for (int k = 0; k < 4; ++k) {
            float cur = s[i * 4 + k];
            int d = 0;
            bool first = (i == 0 && tid == 0 && k == 0);
            if (!first) {
                float g = cur - prev;
                if (fabsf(g) > 0.5f) d = (g > 0.0f) ? 1 : -1;
            }
            s[i * 4 + k] = (cur - (float)running) * TWO_PI - PI_F;
            running += d;
            prev = cur;
        }
    }

    // publish corrected edges; issue mag loads so they fly through barrier C
    if (lane == 63) {
        #pragma unroll
        for (int i = 0; i < NCH; ++i) corrR[i][wv] = s[i * 4 + 3];
    }
    if (lane == 0) {
        #pragma unroll
        for (int i = 0; i < NCH; ++i) corrL[i][wv] = s[i * 4 + 0];
    }
    float4 mg[NCH];
    #pragma unroll
    for (int i = 0; i < NCH; ++i)
        mg[i] = *reinterpret_cast<const float4*>(mag_row + i * CHSZ + tid * 4);
    __syncthreads();                                   // barrier C

    // ---- 5. smooth + blend + range-reduced cos/sin + coalesced store
    #pragma unroll
    for (int i = 0; i < NCH; ++i) {
        float left = __shfl_up(s[i * 4 + 3], 1);
        if (lane == 0) {
            if (wv > 0)      left = corrR[i][wv - 1];
            else if (i > 0)  left = corrR[i - 1][NWAVE - 1];
            else             left = 0.0f;              // zero pad at t==0
        }
        float right = __shfl_down(s[i * 4 + 0], 1);
        if (lane == 63) {
            if (wv < NWAVE - 1)  right = corrL[i][wv + 1];
            else if (i < NCH - 1) right = corrL[i + 1][0];
            else                  right = 0.0f;        // zero pad at t==N-1
        }

        float mgk[4] = {mg[i].x, mg[i].y, mg[i].z, mg[i].w};
        float re[4], im[4];
        #pragma unroll
        for (int k = 0; k < 4; ++k) {
            float pm = (k == 0) ? left  : s[i * 4 + k - 1];
            float pp = (k == 3) ? right : s[i * 4 + k + 1];
            float cur = s[i * 4 + k];
            float sm = ((pm + cur) + pp) * THIRD;
            float pf = 0.7f * cur + 0.3f * sm;
            // two-term range reduction: 2pi = hi + lo
            float nrev = rintf(pf * 0.15915494309189535f);
            float rr = fmaf(nrev, -6.28318548202514648f, pf);
            rr = fmaf(nrev, 1.74845553e-7f, rr);
            re[k] = mgk[k] * __cosf(rr);
            if (MODE == 1) im[k] = mgk[k] * __sinf(rr);
        }
        if (MODE == 0) {
            float* o = out + (size_t)r * N_T + i * CHSZ + tid * 4;
            *reinterpret_cast<float4*>(o) = make_float4(re[0], re[1], re[2], re[3]);
        } else {
            float* o = out + (size_t)r * (2 * N_T) + 2 * (i * CHSZ + tid * 4);
            *reinterpret_cast<float4*>(o)     = make_float4(re[0], im[0], re[1], im[1]);
            *reinterpret_cast<float4*>(o + 4) = make_float4(re[2], im[2], re[3], im[3]);
        }
    }
}

extern "C" void kernel_launch(void* const* d_in, const int* in_sizes, int n_in,
                              void* d_out, int out_size, void* d_ws, size_t ws_size,
                              hipStream_t stream) {
    const float* x = (const float*)d_in[0];
    float* out = (float*)d_out;
    int n_rows = in_sizes[0] / (2 * N_T);              // 1024
    if (out_size >= in_sizes[0]) {
        phase_kernel<1><<<n_rows, BLOCK, 0, stream>>>(x, out);
    } else {
        phase_kernel<0><<<n_rows, BLOCK, 0, stream>>>(x, out);
    }
}